// Round 9
// baseline (419.806 us; speedup 1.0000x reference)
//
#include <hip/hip_runtime.h>

// Vector Quantizer (VQ-VAE) forward on MI355X.
// N=131072 rows, D=64, K=1024 codes, all fp32.
// Output (flat fp32): quantized[8388608] | loss[1] | perplexity[1] | indices[131072]
//
// Numerics (PROVEN round 3 — do not change): replicate np's fp32 distances
//   d_k = fp32( fp32(||x||^2 + ||e_k||^2) - fp32(2 * (x . e_k)) ), first-min argmin,
// dot = single sequential fmaf chain over d=0..63, decisive ops via __f*_rn.
//
// Perf history: 441 (alloca->scratch) -> 704 -> 336 (named regs) -> 335
// (launch_bounds no-op) -> 338 (waves_per_eu(4,4) + SMEM e-loads: spills gone,
// WRITE 52->37.7MB, VGPR 64, but VALU still 298cy/k vs 140 ideal -> ~80 extra
// VALU/k = s->v movs inserted by ISel between SMEM e and the FMA).
// R9: pin each FMA as asm "v_fmac_f32 acc, s_e, v_x" (sgpr src0 legal, 1 sgpr
// read) -> movs impossible. Chain order d=0..63 unchanged (bit-exact).
// Floor: 2048 k/SIMD * ~150cy = 307K cy = 128us.

#define N_ROWS   131072
#define K_CODES  1024
#define DIM      64
#define OUT_LOSS 8388608
#define OUT_PERP 8388609
#define OUT_IDX  8388610

typedef __attribute__((ext_vector_type(16))) float fvec16;

// ---------------- ws layout ----------------
// [0,8)        double sse
// [8,16)       pad
// [16,4112)    uint counts[1024]
// [4112,8208)  float embnorm[1024]

__global__ __launch_bounds__(256) void embnorm_kernel(const float* __restrict__ emb,
                                                      float* __restrict__ norms) {
    int k = blockIdx.x * blockDim.x + threadIdx.x;
    if (k < K_CODES) {
        const float* e = emb + (size_t)k * DIM;
        float r[8];
#pragma unroll
        for (int j = 0; j < 8; ++j) r[j] = __fmul_rn(e[j], e[j]);
#pragma unroll
        for (int i = 8; i < DIM; i += 8)
#pragma unroll
            for (int j = 0; j < 8; ++j) r[j] = __fadd_rn(r[j], __fmul_rn(e[i + j], e[i + j]));
        norms[k] = __fadd_rn(__fadd_rn(__fadd_rn(r[0], r[1]), __fadd_rn(r[2], r[3])),
                             __fadd_rn(__fadd_rn(r[4], r[5]), __fadd_rn(r[6], r[7])));
    }
}

__global__ __launch_bounds__(256)
__attribute__((amdgpu_waves_per_eu(4, 4)))
void vq_kernel(const float* __restrict__ inp,
               const float* __restrict__ emb,
               const float* __restrict__ norms,
               float* __restrict__ out,
               unsigned int* __restrict__ counts,
               double* __restrict__ sse) {
    const int tid  = threadIdx.x;
    const int rloc = tid & 127;
    // wave-uniform half index (waves 0,1 -> half 0; waves 2,3 -> half 1).
    const int half = __builtin_amdgcn_readfirstlane(tid >> 7);
    const int row  = blockIdx.x * 128 + rloc;

    // ---- x row in 16 NAMED float4 registers (no alloca -> no scratch) ----
    const float4* xp = reinterpret_cast<const float4*>(inp + (size_t)row * DIM);
#define DECLX(i) float4 x##i = xp[i];
    DECLX(0)  DECLX(1)  DECLX(2)  DECLX(3)
    DECLX(4)  DECLX(5)  DECLX(6)  DECLX(7)
    DECLX(8)  DECLX(9)  DECLX(10) DECLX(11)
    DECLX(12) DECLX(13) DECLX(14) DECLX(15)

    // ---- s1 = ||x||^2, numpy 8-accumulator pairwise pattern (stride-8) ----
    float r0 = __fmul_rn(x0.x, x0.x), r1 = __fmul_rn(x0.y, x0.y);
    float r2 = __fmul_rn(x0.z, x0.z), r3 = __fmul_rn(x0.w, x0.w);
    float r4 = __fmul_rn(x1.x, x1.x), r5 = __fmul_rn(x1.y, x1.y);
    float r6 = __fmul_rn(x1.z, x1.z), r7 = __fmul_rn(x1.w, x1.w);
#define S1ACC(e, o) \
    r0 = __fadd_rn(r0, __fmul_rn(x##e.x, x##e.x)); \
    r1 = __fadd_rn(r1, __fmul_rn(x##e.y, x##e.y)); \
    r2 = __fadd_rn(r2, __fmul_rn(x##e.z, x##e.z)); \
    r3 = __fadd_rn(r3, __fmul_rn(x##e.w, x##e.w)); \
    r4 = __fadd_rn(r4, __fmul_rn(x##o.x, x##o.x)); \
    r5 = __fadd_rn(r5, __fmul_rn(x##o.y, x##o.y)); \
    r6 = __fadd_rn(r6, __fmul_rn(x##o.z, x##o.z)); \
    r7 = __fadd_rn(r7, __fmul_rn(x##o.w, x##o.w));
    S1ACC(2, 3) S1ACC(4, 5) S1ACC(6, 7) S1ACC(8, 9)
    S1ACC(10, 11) S1ACC(12, 13) S1ACC(14, 15)
    const float s1 = __fadd_rn(__fadd_rn(__fadd_rn(r0, r1), __fadd_rn(r2, r3)),
                               __fadd_rn(__fadd_rn(r4, r5), __fadd_rn(r6, r7)));

    // ---- argmin over this wave's 512-code half; np fp32 rounding exact ----
    const int kbeg = half << 9;
    const float* ebase = emb + ((size_t)kbeg << 6);   // wave-uniform
    const float* np_   = norms + kbeg;
    float best = 3.402823466e38f;
    int   bidx = 0;

#pragma unroll 1
    for (int kk = 0; kk < 512; ++kk) {
        // e row (256B) via wave-uniform scalar loads -> SGPRs, zero VGPR cost.
        fvec16 e0, e1, e2, e3;
        asm volatile(
            "s_load_dwordx16 %0, %4, 0x0\n\t"
            "s_load_dwordx16 %1, %4, 0x40\n\t"
            "s_load_dwordx16 %2, %4, 0x80\n\t"
            "s_load_dwordx16 %3, %4, 0xc0\n\t"
            "s_waitcnt lgkmcnt(0)"
            : "=s"(e0), "=s"(e1), "=s"(e2), "=s"(e3)
            : "s"(ebase));
        // 64 pinned v_fmac_f32 acc, s_e, v_x : sgpr src0 (1 sgpr read, legal),
        // no s->v mov can be inserted. Order = d ascending (bit-exact chain).
        float acc = 0.f;
#define FMAC(ee, j, xs) asm("v_fmac_f32 %0, %1, %2" : "+v"(acc) : "s"(ee[j]), "v"(xs));
        FMAC(e0, 0,  x0.x)  FMAC(e0, 1,  x0.y)  FMAC(e0, 2,  x0.z)  FMAC(e0, 3,  x0.w)
        FMAC(e0, 4,  x1.x)  FMAC(e0, 5,  x1.y)  FMAC(e0, 6,  x1.z)  FMAC(e0, 7,  x1.w)
        FMAC(e0, 8,  x2.x)  FMAC(e0, 9,  x2.y)  FMAC(e0, 10, x2.z)  FMAC(e0, 11, x2.w)
        FMAC(e0, 12, x3.x)  FMAC(e0, 13, x3.y)  FMAC(e0, 14, x3.z)  FMAC(e0, 15, x3.w)
        FMAC(e1, 0,  x4.x)  FMAC(e1, 1,  x4.y)  FMAC(e1, 2,  x4.z)  FMAC(e1, 3,  x4.w)
        FMAC(e1, 4,  x5.x)  FMAC(e1, 5,  x5.y)  FMAC(e1, 6,  x5.z)  FMAC(e1, 7,  x5.w)
        FMAC(e1, 8,  x6.x)  FMAC(e1, 9,  x6.y)  FMAC(e1, 10, x6.z)  FMAC(e1, 11, x6.w)
        FMAC(e1, 12, x7.x)  FMAC(e1, 13, x7.y)  FMAC(e1, 14, x7.z)  FMAC(e1, 15, x7.w)
        FMAC(e2, 0,  x8.x)  FMAC(e2, 1,  x8.y)  FMAC(e2, 2,  x8.z)  FMAC(e2, 3,  x8.w)
        FMAC(e2, 4,  x9.x)  FMAC(e2, 5,  x9.y)  FMAC(e2, 6,  x9.z)  FMAC(e2, 7,  x9.w)
        FMAC(e2, 8,  x10.x) FMAC(e2, 9,  x10.y) FMAC(e2, 10, x10.z) FMAC(e2, 11, x10.w)
        FMAC(e2, 12, x11.x) FMAC(e2, 13, x11.y) FMAC(e2, 14, x11.z) FMAC(e2, 15, x11.w)
        FMAC(e3, 0,  x12.x) FMAC(e3, 1,  x12.y) FMAC(e3, 2,  x12.z) FMAC(e3, 3,  x12.w)
        FMAC(e3, 4,  x13.x) FMAC(e3, 5,  x13.y) FMAC(e3, 6,  x13.z) FMAC(e3, 7,  x13.w)
        FMAC(e3, 8,  x14.x) FMAC(e3, 9,  x14.y) FMAC(e3, 10, x14.z) FMAC(e3, 11, x14.w)
        FMAC(e3, 12, x15.x) FMAC(e3, 13, x15.y) FMAC(e3, 14, x15.z) FMAC(e3, 15, x15.w)
        float Dk = __fsub_rn(__fadd_rn(s1, np_[kk]), __fmul_rn(2.0f, acc));
        if (Dk < best) { best = Dk; bidx = kbeg + kk; }   // strict <: first wins
        ebase += DIM;
    }

    // ---- merge halves (strict <: lower-k half wins ties == np first-min) ----
    __shared__ float sbest[256];
    __shared__ int   sidx[256];
    __shared__ float red[256];
    sbest[tid] = best;
    sidx[tid]  = bidx;
    __syncthreads();

    float err = 0.f;
    if (tid < 128) {
        float ob = sbest[tid + 128];
        int   oi = sidx[tid + 128];
        if (ob < best) { best = ob; bidx = oi; }

        const float4* eb = reinterpret_cast<const float4*>(emb) + ((size_t)bidx << 4);
        float4* qo = reinterpret_cast<float4*>(out + (size_t)row * DIM);
#define EPI(i) { float4 ev = eb[i]; qo[i] = ev; \
    float dx = ev.x - x##i.x, dy = ev.y - x##i.y; \
    float dz = ev.z - x##i.z, dw = ev.w - x##i.w; \
    err += dx * dx + dy * dy + dz * dz + dw * dw; }
        EPI(0)  EPI(1)  EPI(2)  EPI(3)
        EPI(4)  EPI(5)  EPI(6)  EPI(7)
        EPI(8)  EPI(9)  EPI(10) EPI(11)
        EPI(12) EPI(13) EPI(14) EPI(15)

        out[OUT_IDX + row] = (float)bidx;
        atomicAdd(&counts[bidx], 1u);
    }

    red[tid] = err;
    __syncthreads();
#pragma unroll
    for (int s = 128; s > 0; s >>= 1) {
        if (tid < s) red[tid] += red[tid + s];
        __syncthreads();
    }
    if (tid == 0) atomicAdd(sse, (double)red[0]);
}

__global__ __launch_bounds__(1024) void finalize_kernel(const unsigned int* __restrict__ counts,
                                                        const double* __restrict__ sse,
                                                        float* __restrict__ out) {
    __shared__ double red[1024];
    const int t = threadIdx.x;
    double p = (double)counts[t] / (double)N_ROWS;
    red[t] = -p * log(p + 1e-10);
    __syncthreads();
#pragma unroll
    for (int s = 512; s > 0; s >>= 1) {
        if (t < s) red[t] += red[t + s];
        __syncthreads();
    }
    if (t == 0) {
        out[OUT_PERP] = (float)exp(red[0]);
        out[OUT_LOSS] = (float)(1.25 * (*sse) / (double)((size_t)N_ROWS * DIM));
    }
}

extern "C" void kernel_launch(void* const* d_in, const int* in_sizes, int n_in,
                              void* d_out, int out_size, void* d_ws, size_t ws_size,
                              hipStream_t stream) {
    const float* inp = (const float*)d_in[0];   // [32,64,64,64]
    const float* emb = (const float*)d_in[1];   // [1024,64]
    float* out = (float*)d_out;

    double*       sse    = (double*)d_ws;
    unsigned int* counts = (unsigned int*)((char*)d_ws + 16);
    float*        norms  = (float*)((char*)d_ws + 4112);

    hipMemsetAsync(d_ws, 0, 4112, stream);   // sse + counts
    embnorm_kernel<<<4, 256, 0, stream>>>(emb, norms);
    vq_kernel<<<1024, 256, 0, stream>>>(inp, emb, norms, out, counts, sse);
    finalize_kernel<<<1, 1024, 0, stream>>>(counts, sse, out);
}

// Round 11
// 376.066 us; speedup vs baseline: 1.1163x; 1.1163x over previous
//
#include <hip/hip_runtime.h>

// Vector Quantizer (VQ-VAE) forward on MI355X.
// N=131072 rows, D=64, K=1024 codes, all fp32.
// Output (flat fp32): quantized[8388608] | loss[1] | perplexity[1] | indices[131072]
//
// Numerics (PROVEN round 3 — do not change): replicate np's fp32 distances
//   d_k = fp32( fp32(||x||^2 + ||e_k||^2) - fp32(2 * (x . e_k)) ), first-min argmin,
// dot = single sequential fmaf chain over d=0..63, decisive ops via __f*_rn.
//
// Perf history: 441 (alloca->scratch) -> 704 -> 336 (named regs) -> 335 -> 338
// (SMEM e-loads, spills gone) -> 371 (pinned v_fmac asm: VALU cy/k unchanged ->
// wall-vs-FMA gap is SMEM latency serialization, not instruction count).
// R10 (fixed R10 compile bug: p##1.x pasting -> s1 now an inline function):
// 2 ROWS PER THREAD. Each e s_load feeds 128 FMAs (2 independent chains):
// compute/k ~270cy > SMEM latency -> latency hidden within the wave, convoy
// moot. 512 blocks x 4 waves = 2 waves/SIMD; waves_per_eu(2,2) -> 256-VGPR
// budget for 128 x-regs + temps. Floor: ~283K cy/SIMD = ~118us.

#define N_ROWS   131072
#define K_CODES  1024
#define DIM      64
#define OUT_LOSS 8388608
#define OUT_PERP 8388609
#define OUT_IDX  8388610

typedef __attribute__((ext_vector_type(16))) float fvec16;

// ---------------- ws layout ----------------
// [0,8)        double sse
// [8,16)       pad
// [16,4112)    uint counts[1024]
// [4112,8208)  float embnorm[1024]

__global__ __launch_bounds__(256) void embnorm_kernel(const float* __restrict__ emb,
                                                      float* __restrict__ norms) {
    int k = blockIdx.x * blockDim.x + threadIdx.x;
    if (k < K_CODES) {
        const float* e = emb + (size_t)k * DIM;
        float r[8];
#pragma unroll
        for (int j = 0; j < 8; ++j) r[j] = __fmul_rn(e[j], e[j]);
#pragma unroll
        for (int i = 8; i < DIM; i += 8)
#pragma unroll
            for (int j = 0; j < 8; ++j) r[j] = __fadd_rn(r[j], __fmul_rn(e[i + j], e[i + j]));
        norms[k] = __fadd_rn(__fadd_rn(__fadd_rn(r[0], r[1]), __fadd_rn(r[2], r[3])),
                             __fadd_rn(__fadd_rn(r[4], r[5]), __fadd_rn(r[6], r[7])));
    }
}

// s1 = ||x||^2, numpy 8-accumulator pairwise pattern (stride-8), contraction-free.
__device__ __forceinline__ float s1row(float4 x0, float4 x1, float4 x2, float4 x3,
                                       float4 x4, float4 x5, float4 x6, float4 x7,
                                       float4 x8, float4 x9, float4 x10, float4 x11,
                                       float4 x12, float4 x13, float4 x14, float4 x15) {
    float r0 = __fmul_rn(x0.x, x0.x), r1 = __fmul_rn(x0.y, x0.y);
    float r2 = __fmul_rn(x0.z, x0.z), r3 = __fmul_rn(x0.w, x0.w);
    float r4 = __fmul_rn(x1.x, x1.x), r5 = __fmul_rn(x1.y, x1.y);
    float r6 = __fmul_rn(x1.z, x1.z), r7 = __fmul_rn(x1.w, x1.w);
#define S1ACC(e, o) \
    r0 = __fadd_rn(r0, __fmul_rn(x##e.x, x##e.x)); \
    r1 = __fadd_rn(r1, __fmul_rn(x##e.y, x##e.y)); \
    r2 = __fadd_rn(r2, __fmul_rn(x##e.z, x##e.z)); \
    r3 = __fadd_rn(r3, __fmul_rn(x##e.w, x##e.w)); \
    r4 = __fadd_rn(r4, __fmul_rn(x##o.x, x##o.x)); \
    r5 = __fadd_rn(r5, __fmul_rn(x##o.y, x##o.y)); \
    r6 = __fadd_rn(r6, __fmul_rn(x##o.z, x##o.z)); \
    r7 = __fadd_rn(r7, __fmul_rn(x##o.w, x##o.w));
    S1ACC(2, 3) S1ACC(4, 5) S1ACC(6, 7) S1ACC(8, 9)
    S1ACC(10, 11) S1ACC(12, 13) S1ACC(14, 15)
#undef S1ACC
    return __fadd_rn(__fadd_rn(__fadd_rn(r0, r1), __fadd_rn(r2, r3)),
                     __fadd_rn(__fadd_rn(r4, r5), __fadd_rn(r6, r7)));
}

__global__ __launch_bounds__(256)
__attribute__((amdgpu_waves_per_eu(2, 2)))
void vq_kernel(const float* __restrict__ inp,
               const float* __restrict__ emb,
               const float* __restrict__ norms,
               float* __restrict__ out,
               unsigned int* __restrict__ counts,
               double* __restrict__ sse) {
    const int tid   = threadIdx.x;
    const int lane  = tid & 63;
    // set: waves 0,1 -> rows [0,128); waves 2,3 -> rows [128,256) of this block.
    // khalf: even wave -> codes [0,512); odd wave -> codes [512,1024).
    const int set   = __builtin_amdgcn_readfirstlane(tid >> 7);
    const int khalf = __builtin_amdgcn_readfirstlane((tid >> 6) & 1);
    const int row1  = blockIdx.x * 256 + set * 128 + lane;
    const int row2  = row1 + 64;

    // ---- two x rows in 32 NAMED float4 registers (no alloca -> no scratch) ----
    const float4* ap = reinterpret_cast<const float4*>(inp + (size_t)row1 * DIM);
    const float4* bp = reinterpret_cast<const float4*>(inp + (size_t)row2 * DIM);
#define DECLX(i) float4 a##i = ap[i]; float4 b##i = bp[i];
    DECLX(0)  DECLX(1)  DECLX(2)  DECLX(3)
    DECLX(4)  DECLX(5)  DECLX(6)  DECLX(7)
    DECLX(8)  DECLX(9)  DECLX(10) DECLX(11)
    DECLX(12) DECLX(13) DECLX(14) DECLX(15)

    const float s1a = s1row(a0, a1, a2, a3, a4, a5, a6, a7,
                            a8, a9, a10, a11, a12, a13, a14, a15);
    const float s1b = s1row(b0, b1, b2, b3, b4, b5, b6, b7,
                            b8, b9, b10, b11, b12, b13, b14, b15);

    // ---- argmin over this wave's 512-code half for BOTH rows ----
    const int kbeg = khalf << 9;
    const float* ebase = emb + ((size_t)kbeg << 6);   // wave-uniform
    const float* np_   = norms + kbeg;
    float bestA = 3.402823466e38f, bestB = 3.402823466e38f;
    int   bidxA = 0, bidxB = 0;

#define FM4(acc, xv, ev, b) \
    acc = __builtin_fmaf(xv.x, ev[b + 0], acc); \
    acc = __builtin_fmaf(xv.y, ev[b + 1], acc); \
    acc = __builtin_fmaf(xv.z, ev[b + 2], acc); \
    acc = __builtin_fmaf(xv.w, ev[b + 3], acc);

#pragma unroll 1
    for (int kk = 0; kk < 512; ++kk) {
        // e row (256B) via wave-uniform scalar loads -> SGPRs, zero VGPR cost.
        fvec16 e0, e1, e2, e3;
        asm volatile(
            "s_load_dwordx16 %0, %4, 0x0\n\t"
            "s_load_dwordx16 %1, %4, 0x40\n\t"
            "s_load_dwordx16 %2, %4, 0x80\n\t"
            "s_load_dwordx16 %3, %4, 0xc0\n\t"
            "s_waitcnt lgkmcnt(0)"
            : "=s"(e0), "=s"(e1), "=s"(e2), "=s"(e3)
            : "s"(ebase));
        // Two INDEPENDENT sequential fma chains (d=0..63 each, bit-exact),
        // interleaved for ILP=2 -> dep latency fully covered.
        float accA = 0.f, accB = 0.f;
        FM4(accA, a0,  e0, 0)  FM4(accB, b0,  e0, 0)
        FM4(accA, a1,  e0, 4)  FM4(accB, b1,  e0, 4)
        FM4(accA, a2,  e0, 8)  FM4(accB, b2,  e0, 8)
        FM4(accA, a3,  e0, 12) FM4(accB, b3,  e0, 12)
        FM4(accA, a4,  e1, 0)  FM4(accB, b4,  e1, 0)
        FM4(accA, a5,  e1, 4)  FM4(accB, b5,  e1, 4)
        FM4(accA, a6,  e1, 8)  FM4(accB, b6,  e1, 8)
        FM4(accA, a7,  e1, 12) FM4(accB, b7,  e1, 12)
        FM4(accA, a8,  e2, 0)  FM4(accB, b8,  e2, 0)
        FM4(accA, a9,  e2, 4)  FM4(accB, b9,  e2, 4)
        FM4(accA, a10, e2, 8)  FM4(accB, b10, e2, 8)
        FM4(accA, a11, e2, 12) FM4(accB, b11, e2, 12)
        FM4(accA, a12, e3, 0)  FM4(accB, b12, e3, 0)
        FM4(accA, a13, e3, 4)  FM4(accB, b13, e3, 4)
        FM4(accA, a14, e3, 8)  FM4(accB, b14, e3, 8)
        FM4(accA, a15, e3, 12) FM4(accB, b15, e3, 12)
        float nk = np_[kk];
        float DkA = __fsub_rn(__fadd_rn(s1a, nk), __fmul_rn(2.0f, accA));
        float DkB = __fsub_rn(__fadd_rn(s1b, nk), __fmul_rn(2.0f, accB));
        if (DkA < bestA) { bestA = DkA; bidxA = kbeg + kk; }  // strict <: first wins
        if (DkB < bestB) { bestB = DkB; bidxB = kbeg + kk; }
        ebase += DIM;
    }

    // ---- merge k-halves (tie -> lower half = lower k = np first-min) ----
    __shared__ float sb1[256], sb2[256];
    __shared__ int   si1[256], si2[256];
    __shared__ float red[256];
    sb1[tid] = bestA; si1[tid] = bidxA;
    sb2[tid] = bestB; si2[tid] = bidxB;
    __syncthreads();

    float err = 0.f;
    if ((tid & 64) == 0) {             // waves 0 and 2: merge partner = tid+64
        { float ob = sb1[tid + 64]; int oi = si1[tid + 64];
          if (ob < bestA) { bestA = ob; bidxA = oi; } }
        { float ob = sb2[tid + 64]; int oi = si2[tid + 64];
          if (ob < bestB) { bestB = ob; bidxB = oi; } }

        const float4* eA = reinterpret_cast<const float4*>(emb) + ((size_t)bidxA << 4);
        const float4* eB = reinterpret_cast<const float4*>(emb) + ((size_t)bidxB << 4);
        float4* qA = reinterpret_cast<float4*>(out + (size_t)row1 * DIM);
        float4* qB = reinterpret_cast<float4*>(out + (size_t)row2 * DIM);
#define EPI(i) \
        { float4 ev = eA[i]; qA[i] = ev; \
          float dx = ev.x - a##i.x, dy = ev.y - a##i.y; \
          float dz = ev.z - a##i.z, dw = ev.w - a##i.w; \
          err += dx * dx + dy * dy + dz * dz + dw * dw; } \
        { float4 ev = eB[i]; qB[i] = ev; \
          float dx = ev.x - b##i.x, dy = ev.y - b##i.y; \
          float dz = ev.z - b##i.z, dw = ev.w - b##i.w; \
          err += dx * dx + dy * dy + dz * dz + dw * dw; }
        EPI(0)  EPI(1)  EPI(2)  EPI(3)
        EPI(4)  EPI(5)  EPI(6)  EPI(7)
        EPI(8)  EPI(9)  EPI(10) EPI(11)
        EPI(12) EPI(13) EPI(14) EPI(15)

        out[OUT_IDX + row1] = (float)bidxA;
        out[OUT_IDX + row2] = (float)bidxB;
        atomicAdd(&counts[bidxA], 1u);
        atomicAdd(&counts[bidxB], 1u);
    }

    red[tid] = err;
    __syncthreads();
#pragma unroll
    for (int s = 128; s > 0; s >>= 1) {
        if (tid < s) red[tid] += red[tid + s];
        __syncthreads();
    }
    if (tid == 0) atomicAdd(sse, (double)red[0]);
}

__global__ __launch_bounds__(1024) void finalize_kernel(const unsigned int* __restrict__ counts,
                                                        const double* __restrict__ sse,
                                                        float* __restrict__ out) {
    __shared__ double red[1024];
    const int t = threadIdx.x;
    double p = (double)counts[t] / (double)N_ROWS;
    red[t] = -p * log(p + 1e-10);
    __syncthreads();
#pragma unroll
    for (int s = 512; s > 0; s >>= 1) {
        if (t < s) red[t] += red[t + s];
        __syncthreads();
    }
    if (t == 0) {
        out[OUT_PERP] = (float)exp(red[0]);
        out[OUT_LOSS] = (float)(1.25 * (*sse) / (double)((size_t)N_ROWS * DIM));
    }
}

extern "C" void kernel_launch(void* const* d_in, const int* in_sizes, int n_in,
                              void* d_out, int out_size, void* d_ws, size_t ws_size,
                              hipStream_t stream) {
    const float* inp = (const float*)d_in[0];   // [32,64,64,64]
    const float* emb = (const float*)d_in[1];   // [1024,64]
    float* out = (float*)d_out;

    double*       sse    = (double*)d_ws;
    unsigned int* counts = (unsigned int*)((char*)d_ws + 16);
    float*        norms  = (float*)((char*)d_ws + 4112);

    hipMemsetAsync(d_ws, 0, 4112, stream);   // sse + counts
    embnorm_kernel<<<4, 256, 0, stream>>>(emb, norms);
    vq_kernel<<<512, 256, 0, stream>>>(inp, emb, norms, out, counts, sse);
    finalize_kernel<<<1, 1024, 0, stream>>>(counts, sse, out);
}